// Round 10
// baseline (354.382 us; speedup 1.0000x reference)
//
#include <hip/hip_runtime.h>

#define NUM_USERS 25000
#define NUM_ITEMS 25000
#define N_NODES   50000
#define N_EDGES   800000
#define K         64
#define N_QUERY   4096
#define LRELU     0.2f

#define NBUCKET   196      // row >> 8 ; 196*256 = 50176 >= 50000
#define A1_CHUNK  8192
#define A2_CHUNK  4096
#define BMAX      4608     // bucket capacity: mean 4096, +8 sigma

typedef unsigned short ushort_t;
typedef unsigned long long u64_t;

// out layout: [ xui (4096) | gu (25000 x 256) | gi (25000 x 256) ]
__device__ __forceinline__ size_t node_out_offset(int n) {
    return (size_t)N_QUERY + (size_t)n * 256;
}

// f32 -> bf16 round-to-nearest-even
__device__ __forceinline__ ushort_t f2bf(float x) {
    unsigned u = __float_as_uint(x);
    return (ushort_t)((u + 0x7FFFu + ((u >> 16) & 1u)) >> 16);
}
__device__ __forceinline__ float bf2f(ushort_t v) {
    return __uint_as_float(((unsigned)v) << 16);
}

// ---------------------------------------------------------------------------
// init: ego(f32+bf16) = concat(Gu0, Gi0); layer-0 block of out
// ---------------------------------------------------------------------------
__global__ __launch_bounds__(256) void init_ego_kernel(
    const float* __restrict__ Gu0, const float* __restrict__ Gi0,
    float* __restrict__ ego, ushort_t* __restrict__ egb, float* __restrict__ out)
{
    int tid = blockIdx.x * 256 + threadIdx.x;
    if (tid >= N_NODES * K) return;
    int n = tid >> 6;
    int d = tid & 63;
    float v = (n < NUM_USERS) ? Gu0[tid] : Gi0[tid - NUM_USERS * K];
    ego[tid] = v;
    egb[tid] = f2bf(v);
    out[node_out_offset(n) + d] = v;
}

// ---------------------------------------------------------------------------
// weight transpose: WT[k][m][o][j] = W_m[k][j][o]
// ---------------------------------------------------------------------------
__global__ __launch_bounds__(256) void wtrans_kernel(
    const float* __restrict__ W_gc, const float* __restrict__ W_bi,
    float* __restrict__ WT)
{
    int tid = blockIdx.x * 256 + threadIdx.x;
    if (tid >= 3 * 2 * 64 * 64) return;
    int k   = tid >> 13;
    int m   = (tid >> 12) & 1;
    int idx = tid & 4095;
    int o   = idx >> 6;
    int j   = idx & 63;
    const float* src = m ? W_bi : W_gc;
    WT[tid] = src[k * 4096 + j * 64 + o];
}

// ---------------------------------------------------------------------------
// SORT pass A1: coarse bucket histogram (bucket = row >> 8)
// ---------------------------------------------------------------------------
__global__ __launch_bounds__(256) void bhist_kernel(
    const int* __restrict__ rows, int* __restrict__ bucket_count)
{
    __shared__ int h[NBUCKET];
    int t = threadIdx.x;
    if (t < NBUCKET) h[t] = 0;
    __syncthreads();
    int base = blockIdx.x * A1_CHUNK;
    for (int i = t; i < A1_CHUNK; i += 256) {
        int e = base + i;
        if (e < N_EDGES) atomicAdd(&h[rows[e] >> 8], 1);
    }
    __syncthreads();
    if (t < NBUCKET) atomicAdd(&bucket_count[t], h[t]);
}

// ---------------------------------------------------------------------------
// SORT pass scan: exclusive scan of 196 bucket counts -> gbase(197), cursor
// ---------------------------------------------------------------------------
__global__ __launch_bounds__(256) void bscan_kernel(
    const int* __restrict__ bucket_count,
    int* __restrict__ gbase, int* __restrict__ cursor)
{
    __shared__ int sh[256];
    int t = threadIdx.x;
    sh[t] = (t < NBUCKET) ? bucket_count[t] : 0;
    __syncthreads();
    for (int off = 1; off < 256; off <<= 1) {
        int v = (t >= off) ? sh[t - off] : 0;
        __syncthreads();
        sh[t] += v;
        __syncthreads();
    }
    int excl = (t == 0) ? 0 : sh[t - 1];
    if (t < NBUCKET) { gbase[t] = excl; cursor[t] = excl; }
    if (t == NBUCKET) gbase[NBUCKET] = N_EDGES;
}

// ---------------------------------------------------------------------------
// SORT pass A2: bucket scatter with LDS aggregation. Each block stages 4096
// edges (packed u64 = val32|col16|row16), claims one contiguous run per
// bucket (1 global atomic each), scatters into block-exclusive runs.
// ---------------------------------------------------------------------------
__global__ __launch_bounds__(256) void bscatter_kernel(
    const int* __restrict__ rows, const int* __restrict__ cols,
    const float* __restrict__ vals, int* __restrict__ cursor,
    u64_t* __restrict__ csr64)
{
    __shared__ u64_t recs[A2_CHUNK];
    __shared__ int hist[NBUCKET], lbase[NBUCKET], lcur[NBUCKET];
    int t = threadIdx.x;
    if (t < NBUCKET) { hist[t] = 0; lcur[t] = 0; }
    __syncthreads();
    int base = blockIdx.x * A2_CHUNK;
    for (int i = t; i < A2_CHUNK; i += 256) {
        int e = base + i;
        if (e < N_EDGES) {
            int r = rows[e];
            u64_t rec = ((u64_t)(unsigned)__float_as_uint(vals[e]) << 32)
                      | ((u64_t)(unsigned)cols[e] << 16)
                      | (unsigned)r;
            recs[i] = rec;
            atomicAdd(&hist[r >> 8], 1);
        }
    }
    __syncthreads();
    if (t < NBUCKET) lbase[t] = atomicAdd(&cursor[t], hist[t]);
    __syncthreads();
    for (int i = t; i < A2_CHUNK; i += 256) {
        int e = base + i;
        if (e < N_EDGES) {
            u64_t rec = recs[i];
            int b = (int)((rec >> 8) & 0xFF);          // row>>8
            int dst = lbase[b] + atomicAdd(&lcur[b], 1);
            csr64[dst] = rec;
        }
    }
}

// ---------------------------------------------------------------------------
// SORT pass B: per-bucket counting sort (256 bins on row&255) entirely from
// an LDS copy; writes final (col,val) int2 in place + offs[] for its rows.
// ---------------------------------------------------------------------------
__global__ __launch_bounds__(256) void bsort_kernel(
    const int* __restrict__ gbase, u64_t* __restrict__ csr64,
    int* __restrict__ offs)
{
    __shared__ u64_t recs[BMAX];
    __shared__ int hist[256], lscan[256], lcur[256];
    int b = blockIdx.x, t = threadIdx.x;
    int g0 = gbase[b];
    int nb = gbase[b + 1] - g0;
    if (nb > BMAX) nb = BMAX;                          // unreachable safety
    hist[t] = 0; lcur[t] = 0;
    __syncthreads();
    for (int i = t; i < nb; i += 256) {
        u64_t rec = csr64[g0 + i];
        recs[i] = rec;
        atomicAdd(&hist[(int)(rec & 0xFF)], 1);        // row & 255
    }
    __syncthreads();
    int v0 = hist[t];
    lscan[t] = v0;
    __syncthreads();
    for (int off = 1; off < 256; off <<= 1) {
        int v = (t >= off) ? lscan[t - off] : 0;
        __syncthreads();
        lscan[t] += v;
        __syncthreads();
    }
    int excl = lscan[t] - v0;                          // exclusive scan
    int row = (b << 8) + t;
    if (row < N_NODES) offs[row] = g0 + excl;
    if (b == 0 && t == 0) offs[N_NODES] = N_EDGES;
    __syncthreads();
    lscan[t] = excl;
    __syncthreads();
    for (int i = t; i < nb; i += 256) {
        u64_t rec = recs[i];
        int rl = (int)(rec & 0xFF);
        int pos = lscan[rl] + atomicAdd(&lcur[rl], 1);
        // final format: low32 = col, high32 = val bits (same as gather expects)
        u64_t out = (rec >> 32 << 32) | ((rec >> 16) & 0xFFFFu);
        csr64[g0 + pos] = out;
    }
}

// ---------------------------------------------------------------------------
// gather (dim-half pass): side[n][half*32+d] = sum val_e * egb[col][half*32+d].
// Working set per pass = 3.2 MB -> L2-resident per XCD. Wave processes 2
// edges at once (par = lane>>5), 8-deep ILP. csr stream + side store NT.
// ---------------------------------------------------------------------------
__global__ __launch_bounds__(512, 8) void gather_half_kernel(
    const int* __restrict__ offs, const long long* __restrict__ csr64,
    const ushort_t* __restrict__ egb, float* __restrict__ side, int half)
{
    int t = threadIdx.x;
    int wave = t >> 6;
    int lane = t & 63;
    int par  = lane >> 5;           // which of the 2 edges
    int d    = lane & 31;           // dim within half
    int node = blockIdx.x * 8 + wave;
    const ushort_t* egh = egb + half * 32;

    int beg = offs[node];
    int end = offs[node + 1];
    float acc = 0.f;
    int j = beg;

    for (; j + 16 <= end; j += 16) {           // 8 pairs in flight
        long long cv[8];
        #pragma unroll
        for (int u = 0; u < 8; ++u)
            cv[u] = __builtin_nontemporal_load(csr64 + j + 2 * u + par);
        float gg[8];
        #pragma unroll
        for (int u = 0; u < 8; ++u)
            gg[u] = bf2f(egh[((size_t)(unsigned)(cv[u] & 0xffffffffLL) << 6) + d]);
        #pragma unroll
        for (int u = 0; u < 8; ++u)
            acc = fmaf(__uint_as_float((unsigned)((u64_t)cv[u] >> 32)), gg[u], acc);
    }
    for (; j + 4 <= end; j += 4) {             // 2 pairs
        long long cv[2];
        #pragma unroll
        for (int u = 0; u < 2; ++u)
            cv[u] = __builtin_nontemporal_load(csr64 + j + 2 * u + par);
        float gg[2];
        #pragma unroll
        for (int u = 0; u < 2; ++u)
            gg[u] = bf2f(egh[((size_t)(unsigned)(cv[u] & 0xffffffffLL) << 6) + d]);
        #pragma unroll
        for (int u = 0; u < 2; ++u)
            acc = fmaf(__uint_as_float((unsigned)((u64_t)cv[u] >> 32)), gg[u], acc);
    }
    for (; j + 2 <= end; j += 2) {             // 1 pair
        long long cv = __builtin_nontemporal_load(csr64 + j + par);
        acc = fmaf(__uint_as_float((unsigned)((u64_t)cv >> 32)),
                   bf2f(egh[((size_t)(unsigned)(cv & 0xffffffffLL) << 6) + d]), acc);
    }
    if (j < end && par == 0) {                 // odd tail edge
        long long cv = __builtin_nontemporal_load(csr64 + j);
        acc = fmaf(__uint_as_float((unsigned)((u64_t)cv >> 32)),
                   bf2f(egh[((size_t)(unsigned)(cv & 0xffffffffLL) << 6) + d]), acc);
    }

    acc += __shfl_xor(acc, 32);                // combine the two parities
    if (par == 0)
        __builtin_nontemporal_store(acc, side + ((size_t)node << 6) + half * 32 + d);
}

// ---------------------------------------------------------------------------
// transform: register-tiled f32 GEMM (64 nodes x 64 outs, K=64), 4x4
// micro-tile, XOR-swizzled LDS. Epilogue: bias+lrelu+add, 16-lane norm,
// writes ego(f32), egb(bf16), out.
// ---------------------------------------------------------------------------
__global__ __launch_bounds__(256, 2) void transform_kernel(
    const float* __restrict__ side, float* __restrict__ ego,
    ushort_t* __restrict__ egb,
    const float* __restrict__ WgT, const float* __restrict__ WbT,
    const float* __restrict__ bgc, const float* __restrict__ bbi,
    float* __restrict__ out, int layer_k)
{
    __shared__ float s_s [64 * 64];
    __shared__ float s_es[64 * 64];
    __shared__ float s_wg[64 * 64];
    __shared__ float s_wb[64 * 64];

    int t = threadIdx.x;
    int base = blockIdx.x * 64;

    for (int idx = t; idx < 64 * 16; idx += 256) {
        int r = idx >> 4;
        int q = idx & 15;
        int qs = q ^ ((r >> 2) & 7);
        float4 sv = make_float4(0.f, 0.f, 0.f, 0.f);
        float4 ev = make_float4(0.f, 0.f, 0.f, 0.f);
        int node = base + r;
        if (node < N_NODES) {
            sv = *(const float4*)(side + ((size_t)node << 6) + 4 * q);
            ev = *(const float4*)(ego  + ((size_t)node << 6) + 4 * q);
        }
        *(float4*)&s_s [r * 64 + 4 * qs] = sv;
        *(float4*)&s_es[r * 64 + 4 * qs] =
            make_float4(ev.x * sv.x, ev.y * sv.y, ev.z * sv.z, ev.w * sv.w);
        *(float4*)&s_wg[r * 64 + 4 * qs] = *(const float4*)(WgT + (size_t)r * 64 + 4 * q);
        *(float4*)&s_wb[r * 64 + 4 * qs] = *(const float4*)(WbT + (size_t)r * 64 + 4 * q);
    }
    __syncthreads();

    const int o0  = (t & 15) << 2;
    const int ln0 = (t >> 4) << 2;
    const int sa  = (t >> 4) & 7;
    const int sw  = t & 7;

    float accg[4][4] = {};
    float accb[4][4] = {};

    #pragma unroll 4
    for (int kq = 0; kq < 16; ++kq) {
        const int qa = (kq ^ sa) << 2;
        const int qw = (kq ^ sw) << 2;
        float4 a[4], b[4], wg[4], wb[4];
        #pragma unroll
        for (int i = 0; i < 4; ++i) {
            a[i] = *(const float4*)&s_s [(ln0 + i) * 64 + qa];
            b[i] = *(const float4*)&s_es[(ln0 + i) * 64 + qa];
        }
        #pragma unroll
        for (int j = 0; j < 4; ++j) {
            wg[j] = *(const float4*)&s_wg[(o0 + j) * 64 + qw];
            wb[j] = *(const float4*)&s_wb[(o0 + j) * 64 + qw];
        }
        #pragma unroll
        for (int i = 0; i < 4; ++i) {
            #pragma unroll
            for (int j = 0; j < 4; ++j) {
                accg[i][j] = fmaf(a[i].x, wg[j].x, accg[i][j]);
                accg[i][j] = fmaf(a[i].y, wg[j].y, accg[i][j]);
                accg[i][j] = fmaf(a[i].z, wg[j].z, accg[i][j]);
                accg[i][j] = fmaf(a[i].w, wg[j].w, accg[i][j]);
                accb[i][j] = fmaf(b[i].x, wb[j].x, accb[i][j]);
                accb[i][j] = fmaf(b[i].y, wb[j].y, accb[i][j]);
                accb[i][j] = fmaf(b[i].z, wb[j].z, accb[i][j]);
                accb[i][j] = fmaf(b[i].w, wb[j].w, accb[i][j]);
            }
        }
    }

    float4 bg4 = *(const float4*)(bgc + o0);
    float4 bb4 = *(const float4*)(bbi + o0);
    float bgv[4] = {bg4.x, bg4.y, bg4.z, bg4.w};
    float bbv[4] = {bb4.x, bb4.y, bb4.z, bb4.w};

    #pragma unroll
    for (int i = 0; i < 4; ++i) {
        int node = base + ln0 + i;
        float en[4];
        float ss = 0.f;
        #pragma unroll
        for (int j = 0; j < 4; ++j) {
            float g = accg[i][j] + bgv[j];
            float h = accb[i][j] + bbv[j];
            g = (g > 0.f) ? g : LRELU * g;
            h = (h > 0.f) ? h : LRELU * h;
            en[j] = g + h;
            ss = fmaf(en[j], en[j], ss);
        }
        #pragma unroll
        for (int m = 1; m < 16; m <<= 1) ss += __shfl_xor(ss, m);
        float inv = rsqrtf(fmaxf(ss, 1e-12f));
        if (node < N_NODES) {
            *(float4*)(ego + ((size_t)node << 6) + o0) =
                make_float4(en[0], en[1], en[2], en[3]);
            *(ushort4*)(egb + ((size_t)node << 6) + o0) =
                make_ushort4(f2bf(en[0]), f2bf(en[1]), f2bf(en[2]), f2bf(en[3]));
            *(float4*)(out + node_out_offset(node) + (size_t)(layer_k + 1) * K + o0) =
                make_float4(en[0] * inv, en[1] * inv, en[2] * inv, en[3] * inv);
        }
    }
}

// ---------------------------------------------------------------------------
// readout: xui[i] = dot(gu[user[i]], gi[item[i]]) over 256 dims
// ---------------------------------------------------------------------------
__global__ __launch_bounds__(256) void xui_kernel(
    const int* __restrict__ user, const int* __restrict__ item,
    float* __restrict__ out)
{
    int idx = blockIdx.x * 4 + (threadIdx.x >> 6);
    if (idx >= N_QUERY) return;
    int lane = threadIdx.x & 63;
    int u  = user[idx];
    int it = item[idx];
    const float4* gu = (const float4*)(out + (size_t)N_QUERY + (size_t)u * 256);
    const float4* gi = (const float4*)(out + (size_t)N_QUERY + (size_t)NUM_USERS * 256
                                           + (size_t)it * 256);
    float4 a = gu[lane];
    float4 b = gi[lane];
    float d = a.x * b.x + a.y * b.y + a.z * b.z + a.w * b.w;
    #pragma unroll
    for (int off = 32; off; off >>= 1) d += __shfl_xor(d, off);
    if (lane == 0) out[idx] = d;
}

extern "C" void kernel_launch(void* const* d_in, const int* in_sizes, int n_in,
                              void* d_out, int out_size, void* d_ws, size_t ws_size,
                              hipStream_t stream)
{
    const int*   adj_rows = (const int*)  d_in[0];
    const int*   adj_cols = (const int*)  d_in[1];
    const float* adj_vals = (const float*)d_in[2];
    const float* Gu0      = (const float*)d_in[3];
    const float* Gi0      = (const float*)d_in[4];
    const float* W_gc     = (const float*)d_in[5];
    const float* b_gc     = (const float*)d_in[6];
    const float* W_bi     = (const float*)d_in[7];
    const float* b_bi     = (const float*)d_in[8];
    const int*   user     = (const int*)  d_in[9];
    const int*   item     = (const int*)  d_in[10];

    float* out = (float*)d_out;

    // workspace (~38.7 MB):
    float*    ego    = (float*)d_ws;                              // 12.8 MB
    float*    side   = ego + (size_t)N_NODES * K;                 // 12.8 MB
    ushort_t* egb    = (ushort_t*)(side + (size_t)N_NODES * K);   // 6.4 MB
    u64_t*    csr64  = (u64_t*)(egb + (size_t)N_NODES * K);       // 6.4 MB
    int*      offs   = (int*)(csr64 + N_EDGES);                   // N_NODES+1
    int*      gbase  = offs + N_NODES + 1;                        // NBUCKET+1
    int*      cursor = gbase + NBUCKET + 1;                       // NBUCKET
    int*      bcnt   = cursor + NBUCKET;                          // NBUCKET
    float*    WT     = (float*)(bcnt + NBUCKET);                  // 96 KB

    // ---- two-level counting sort -> csr64 (col,val) + offs ----
    hipMemsetAsync(bcnt, 0, NBUCKET * sizeof(int), stream);
    bhist_kernel<<<(N_EDGES + A1_CHUNK - 1) / A1_CHUNK, 256, 0, stream>>>(adj_rows, bcnt);
    bscan_kernel<<<1, 256, 0, stream>>>(bcnt, gbase, cursor);
    bscatter_kernel<<<(N_EDGES + A2_CHUNK - 1) / A2_CHUNK, 256, 0, stream>>>(
        adj_rows, adj_cols, adj_vals, cursor, csr64);
    bsort_kernel<<<NBUCKET, 256, 0, stream>>>(gbase, csr64, offs);

    // ---- weight transpose + init ego ----
    wtrans_kernel<<<(3 * 2 * 4096 + 255) / 256, 256, 0, stream>>>(W_gc, W_bi, WT);
    init_ego_kernel<<<(N_NODES * K + 255) / 256, 256, 0, stream>>>(Gu0, Gi0, ego, egb, out);

    // ---- 3 layers ----
    for (int k = 0; k < 3; ++k) {
        gather_half_kernel<<<N_NODES / 8, 512, 0, stream>>>(
            offs, (const long long*)csr64, egb, side, 0);
        gather_half_kernel<<<N_NODES / 8, 512, 0, stream>>>(
            offs, (const long long*)csr64, egb, side, 1);
        transform_kernel<<<(N_NODES + 63) / 64, 256, 0, stream>>>(
            side, ego, egb,
            WT + (size_t)k * 8192, WT + (size_t)k * 8192 + 4096,
            b_gc + (size_t)k * K, b_bi + (size_t)k * K,
            out, k);
    }

    xui_kernel<<<N_QUERY / 4, 256, 0, stream>>>(user, item, out);
}

// Round 11
// 267.477 us; speedup vs baseline: 1.3249x; 1.3249x over previous
//
#include <hip/hip_runtime.h>

#define NUM_USERS 25000
#define NUM_ITEMS 25000
#define N_NODES   50000
#define N_EDGES   800000
#define K         64
#define N_QUERY   4096
#define LRELU     0.2f

#define NBUCKET   196      // row >> 8 ; 196*256 = 50176 >= 50000
#define A1_CHUNK  8192
#define A2_CHUNK  4096
#define BMAX      4608     // bucket capacity: mean 4096, +8 sigma

typedef unsigned short ushort_t;
typedef unsigned long long u64_t;

// out layout: [ xui (4096) | gu (25000 x 256) | gi (25000 x 256) ]
__device__ __forceinline__ size_t node_out_offset(int n) {
    return (size_t)N_QUERY + (size_t)n * 256;
}

// f32 -> bf16 round-to-nearest-even
__device__ __forceinline__ ushort_t f2bf(float x) {
    unsigned u = __float_as_uint(x);
    return (ushort_t)((u + 0x7FFFu + ((u >> 16) & 1u)) >> 16);
}
__device__ __forceinline__ float bf2f(ushort_t v) {
    return __uint_as_float(((unsigned)v) << 16);
}

// ---------------------------------------------------------------------------
// init: ego(f32+bf16) = concat(Gu0, Gi0); layer-0 block of out
// ---------------------------------------------------------------------------
__global__ __launch_bounds__(256) void init_ego_kernel(
    const float* __restrict__ Gu0, const float* __restrict__ Gi0,
    float* __restrict__ ego, ushort_t* __restrict__ egb, float* __restrict__ out)
{
    int tid = blockIdx.x * 256 + threadIdx.x;
    if (tid >= N_NODES * K) return;
    int n = tid >> 6;
    int d = tid & 63;
    float v = (n < NUM_USERS) ? Gu0[tid] : Gi0[tid - NUM_USERS * K];
    ego[tid] = v;
    egb[tid] = f2bf(v);
    out[node_out_offset(n) + d] = v;
}

// ---------------------------------------------------------------------------
// weight transpose: WT[k][m][o][j] = W_m[k][j][o]
// ---------------------------------------------------------------------------
__global__ __launch_bounds__(256) void wtrans_kernel(
    const float* __restrict__ W_gc, const float* __restrict__ W_bi,
    float* __restrict__ WT)
{
    int tid = blockIdx.x * 256 + threadIdx.x;
    if (tid >= 3 * 2 * 64 * 64) return;
    int k   = tid >> 13;
    int m   = (tid >> 12) & 1;
    int idx = tid & 4095;
    int o   = idx >> 6;
    int j   = idx & 63;
    const float* src = m ? W_bi : W_gc;
    WT[tid] = src[k * 4096 + j * 64 + o];
}

// ---------------------------------------------------------------------------
// SORT pass A1: coarse bucket histogram (bucket = row >> 8)
// ---------------------------------------------------------------------------
__global__ __launch_bounds__(256) void bhist_kernel(
    const int* __restrict__ rows, int* __restrict__ bucket_count)
{
    __shared__ int h[NBUCKET];
    int t = threadIdx.x;
    if (t < NBUCKET) h[t] = 0;
    __syncthreads();
    int base = blockIdx.x * A1_CHUNK;
    for (int i = t; i < A1_CHUNK; i += 256) {
        int e = base + i;
        if (e < N_EDGES) atomicAdd(&h[rows[e] >> 8], 1);
    }
    __syncthreads();
    if (t < NBUCKET) atomicAdd(&bucket_count[t], h[t]);
}

// ---------------------------------------------------------------------------
// SORT pass scan: exclusive scan of 196 bucket counts -> gbase(197), cursor
// ---------------------------------------------------------------------------
__global__ __launch_bounds__(256) void bscan_kernel(
    const int* __restrict__ bucket_count,
    int* __restrict__ gbase, int* __restrict__ cursor)
{
    __shared__ int sh[256];
    int t = threadIdx.x;
    sh[t] = (t < NBUCKET) ? bucket_count[t] : 0;
    __syncthreads();
    for (int off = 1; off < 256; off <<= 1) {
        int v = (t >= off) ? sh[t - off] : 0;
        __syncthreads();
        sh[t] += v;
        __syncthreads();
    }
    int excl = (t == 0) ? 0 : sh[t - 1];
    if (t < NBUCKET) { gbase[t] = excl; cursor[t] = excl; }
    if (t == NBUCKET) gbase[NBUCKET] = N_EDGES;
}

// ---------------------------------------------------------------------------
// SORT pass A2: bucket scatter with LDS aggregation. Each block stages 4096
// edges (packed u64 = val32|col16|row16), claims one contiguous run per
// bucket (1 global atomic each), scatters into block-exclusive runs.
// ---------------------------------------------------------------------------
__global__ __launch_bounds__(256) void bscatter_kernel(
    const int* __restrict__ rows, const int* __restrict__ cols,
    const float* __restrict__ vals, int* __restrict__ cursor,
    u64_t* __restrict__ csr64)
{
    __shared__ u64_t recs[A2_CHUNK];
    __shared__ int hist[NBUCKET], lbase[NBUCKET], lcur[NBUCKET];
    int t = threadIdx.x;
    if (t < NBUCKET) { hist[t] = 0; lcur[t] = 0; }
    __syncthreads();
    int base = blockIdx.x * A2_CHUNK;
    for (int i = t; i < A2_CHUNK; i += 256) {
        int e = base + i;
        if (e < N_EDGES) {
            int r = rows[e];
            u64_t rec = ((u64_t)(unsigned)__float_as_uint(vals[e]) << 32)
                      | ((u64_t)(unsigned)cols[e] << 16)
                      | (unsigned)r;
            recs[i] = rec;
            atomicAdd(&hist[r >> 8], 1);
        }
    }
    __syncthreads();
    if (t < NBUCKET) lbase[t] = atomicAdd(&cursor[t], hist[t]);
    __syncthreads();
    for (int i = t; i < A2_CHUNK; i += 256) {
        int e = base + i;
        if (e < N_EDGES) {
            u64_t rec = recs[i];
            int b = (int)((rec >> 8) & 0xFF);          // row>>8
            int dst = lbase[b] + atomicAdd(&lcur[b], 1);
            csr64[dst] = rec;
        }
    }
}

// ---------------------------------------------------------------------------
// SORT pass B: per-bucket counting sort (256 bins on row&255) entirely from
// an LDS copy; writes final (col low32, val high32) in place + offs[].
// ---------------------------------------------------------------------------
__global__ __launch_bounds__(256) void bsort_kernel(
    const int* __restrict__ gbase, u64_t* __restrict__ csr64,
    int* __restrict__ offs)
{
    __shared__ u64_t recs[BMAX];
    __shared__ int hist[256], lscan[256], lcur[256];
    int b = blockIdx.x, t = threadIdx.x;
    int g0 = gbase[b];
    int nb = gbase[b + 1] - g0;
    if (nb > BMAX) nb = BMAX;                          // unreachable safety
    hist[t] = 0; lcur[t] = 0;
    __syncthreads();
    for (int i = t; i < nb; i += 256) {
        u64_t rec = csr64[g0 + i];
        recs[i] = rec;
        atomicAdd(&hist[(int)(rec & 0xFF)], 1);        // row & 255
    }
    __syncthreads();
    int v0 = hist[t];
    lscan[t] = v0;
    __syncthreads();
    for (int off = 1; off < 256; off <<= 1) {
        int v = (t >= off) ? lscan[t - off] : 0;
        __syncthreads();
        lscan[t] += v;
        __syncthreads();
    }
    int excl = lscan[t] - v0;                          // exclusive scan
    int row = (b << 8) + t;
    if (row < N_NODES) offs[row] = g0 + excl;
    if (b == 0 && t == 0) offs[N_NODES] = N_EDGES;
    __syncthreads();
    lscan[t] = excl;
    __syncthreads();
    for (int i = t; i < nb; i += 256) {
        u64_t rec = recs[i];
        int rl = (int)(rec & 0xFF);
        int pos = lscan[rl] + atomicAdd(&lcur[rl], 1);
        // final format: low32 = col, high32 = val bits (gather's layout)
        u64_t outrec = (rec >> 32 << 32) | ((rec >> 16) & 0xFFFFu);
        csr64[g0 + pos] = outrec;
    }
}

// ---------------------------------------------------------------------------
// gather: side[n][lane] = sum_e val_e * ego_bf16[col_e][lane] (f32 accum).
// csr sequential 8B stream (nontemporal); ego rows bf16 (128B).
// 512 threads = 8 waves = 8 nodes/block; grid 6250. 12-deep ILP.
// ---------------------------------------------------------------------------
__global__ __launch_bounds__(512, 8) void gather_kernel(
    const int* __restrict__ offs, const long long* __restrict__ csr_cv,
    const ushort_t* __restrict__ egb, float* __restrict__ side)
{
    int t = threadIdx.x;
    int wave = t >> 6;
    int lane = t & 63;
    int node = blockIdx.x * 8 + wave;

    int beg = offs[node];
    int end = offs[node + 1];
    float acc = 0.f;
    int j = beg;

    for (; j + 12 <= end; j += 12) {
        long long cvp[12];
        #pragma unroll
        for (int u = 0; u < 12; ++u) cvp[u] = __builtin_nontemporal_load(csr_cv + j + u);
        float gg[12];
        #pragma unroll
        for (int u = 0; u < 12; ++u)
            gg[u] = bf2f(egb[((size_t)(unsigned int)(cvp[u] & 0xffffffffLL) << 6) + lane]);
        #pragma unroll
        for (int u = 0; u < 12; ++u)
            acc = fmaf(__uint_as_float((unsigned int)((u64_t)cvp[u] >> 32)), gg[u], acc);
    }
    for (; j + 4 <= end; j += 4) {
        long long cvp[4];
        #pragma unroll
        for (int u = 0; u < 4; ++u) cvp[u] = __builtin_nontemporal_load(csr_cv + j + u);
        float gg[4];
        #pragma unroll
        for (int u = 0; u < 4; ++u)
            gg[u] = bf2f(egb[((size_t)(unsigned int)(cvp[u] & 0xffffffffLL) << 6) + lane]);
        #pragma unroll
        for (int u = 0; u < 4; ++u)
            acc = fmaf(__uint_as_float((unsigned int)((u64_t)cvp[u] >> 32)), gg[u], acc);
    }
    for (; j < end; ++j) {
        long long cvp = __builtin_nontemporal_load(csr_cv + j);
        acc = fmaf(__uint_as_float((unsigned int)((u64_t)cvp >> 32)),
                   bf2f(egb[((size_t)(unsigned int)(cvp & 0xffffffffLL) << 6) + lane]), acc);
    }

    side[((size_t)node << 6) + lane] = acc;
}

// ---------------------------------------------------------------------------
// transform: register-tiled f32 GEMM (64 nodes x 64 outs, K=64), 4x4
// micro-tile, XOR-swizzled LDS. Epilogue: bias+lrelu+add, 16-lane norm,
// writes ego(f32), egb(bf16), out.
// ---------------------------------------------------------------------------
__global__ __launch_bounds__(256, 2) void transform_kernel(
    const float* __restrict__ side, float* __restrict__ ego,
    ushort_t* __restrict__ egb,
    const float* __restrict__ WgT, const float* __restrict__ WbT,
    const float* __restrict__ bgc, const float* __restrict__ bbi,
    float* __restrict__ out, int layer_k)
{
    __shared__ float s_s [64 * 64];
    __shared__ float s_es[64 * 64];
    __shared__ float s_wg[64 * 64];
    __shared__ float s_wb[64 * 64];

    int t = threadIdx.x;
    int base = blockIdx.x * 64;

    for (int idx = t; idx < 64 * 16; idx += 256) {
        int r = idx >> 4;
        int q = idx & 15;
        int qs = q ^ ((r >> 2) & 7);
        float4 sv = make_float4(0.f, 0.f, 0.f, 0.f);
        float4 ev = make_float4(0.f, 0.f, 0.f, 0.f);
        int node = base + r;
        if (node < N_NODES) {
            sv = *(const float4*)(side + ((size_t)node << 6) + 4 * q);
            ev = *(const float4*)(ego  + ((size_t)node << 6) + 4 * q);
        }
        *(float4*)&s_s [r * 64 + 4 * qs] = sv;
        *(float4*)&s_es[r * 64 + 4 * qs] =
            make_float4(ev.x * sv.x, ev.y * sv.y, ev.z * sv.z, ev.w * sv.w);
        *(float4*)&s_wg[r * 64 + 4 * qs] = *(const float4*)(WgT + (size_t)r * 64 + 4 * q);
        *(float4*)&s_wb[r * 64 + 4 * qs] = *(const float4*)(WbT + (size_t)r * 64 + 4 * q);
    }
    __syncthreads();

    const int o0  = (t & 15) << 2;
    const int ln0 = (t >> 4) << 2;
    const int sa  = (t >> 4) & 7;
    const int sw  = t & 7;

    float accg[4][4] = {};
    float accb[4][4] = {};

    #pragma unroll 4
    for (int kq = 0; kq < 16; ++kq) {
        const int qa = (kq ^ sa) << 2;
        const int qw = (kq ^ sw) << 2;
        float4 a[4], b[4], wg[4], wb[4];
        #pragma unroll
        for (int i = 0; i < 4; ++i) {
            a[i] = *(const float4*)&s_s [(ln0 + i) * 64 + qa];
            b[i] = *(const float4*)&s_es[(ln0 + i) * 64 + qa];
        }
        #pragma unroll
        for (int j = 0; j < 4; ++j) {
            wg[j] = *(const float4*)&s_wg[(o0 + j) * 64 + qw];
            wb[j] = *(const float4*)&s_wb[(o0 + j) * 64 + qw];
        }
        #pragma unroll
        for (int i = 0; i < 4; ++i) {
            #pragma unroll
            for (int j = 0; j < 4; ++j) {
                accg[i][j] = fmaf(a[i].x, wg[j].x, accg[i][j]);
                accg[i][j] = fmaf(a[i].y, wg[j].y, accg[i][j]);
                accg[i][j] = fmaf(a[i].z, wg[j].z, accg[i][j]);
                accg[i][j] = fmaf(a[i].w, wg[j].w, accg[i][j]);
                accb[i][j] = fmaf(b[i].x, wb[j].x, accb[i][j]);
                accb[i][j] = fmaf(b[i].y, wb[j].y, accb[i][j]);
                accb[i][j] = fmaf(b[i].z, wb[j].z, accb[i][j]);
                accb[i][j] = fmaf(b[i].w, wb[j].w, accb[i][j]);
            }
        }
    }

    float4 bg4 = *(const float4*)(bgc + o0);
    float4 bb4 = *(const float4*)(bbi + o0);
    float bgv[4] = {bg4.x, bg4.y, bg4.z, bg4.w};
    float bbv[4] = {bb4.x, bb4.y, bb4.z, bb4.w};

    #pragma unroll
    for (int i = 0; i < 4; ++i) {
        int node = base + ln0 + i;
        float en[4];
        float ss = 0.f;
        #pragma unroll
        for (int j = 0; j < 4; ++j) {
            float g = accg[i][j] + bgv[j];
            float h = accb[i][j] + bbv[j];
            g = (g > 0.f) ? g : LRELU * g;
            h = (h > 0.f) ? h : LRELU * h;
            en[j] = g + h;
            ss = fmaf(en[j], en[j], ss);
        }
        #pragma unroll
        for (int m = 1; m < 16; m <<= 1) ss += __shfl_xor(ss, m);
        float inv = rsqrtf(fmaxf(ss, 1e-12f));
        if (node < N_NODES) {
            *(float4*)(ego + ((size_t)node << 6) + o0) =
                make_float4(en[0], en[1], en[2], en[3]);
            *(ushort4*)(egb + ((size_t)node << 6) + o0) =
                make_ushort4(f2bf(en[0]), f2bf(en[1]), f2bf(en[2]), f2bf(en[3]));
            *(float4*)(out + node_out_offset(node) + (size_t)(layer_k + 1) * K + o0) =
                make_float4(en[0] * inv, en[1] * inv, en[2] * inv, en[3] * inv);
        }
    }
}

// ---------------------------------------------------------------------------
// readout: xui[i] = dot(gu[user[i]], gi[item[i]]) over 256 dims
// ---------------------------------------------------------------------------
__global__ __launch_bounds__(256) void xui_kernel(
    const int* __restrict__ user, const int* __restrict__ item,
    float* __restrict__ out)
{
    int idx = blockIdx.x * 4 + (threadIdx.x >> 6);
    if (idx >= N_QUERY) return;
    int lane = threadIdx.x & 63;
    int u  = user[idx];
    int it = item[idx];
    const float4* gu = (const float4*)(out + (size_t)N_QUERY + (size_t)u * 256);
    const float4* gi = (const float4*)(out + (size_t)N_QUERY + (size_t)NUM_USERS * 256
                                           + (size_t)it * 256);
    float4 a = gu[lane];
    float4 b = gi[lane];
    float d = a.x * b.x + a.y * b.y + a.z * b.z + a.w * b.w;
    #pragma unroll
    for (int off = 32; off; off >>= 1) d += __shfl_xor(d, off);
    if (lane == 0) out[idx] = d;
}

extern "C" void kernel_launch(void* const* d_in, const int* in_sizes, int n_in,
                              void* d_out, int out_size, void* d_ws, size_t ws_size,
                              hipStream_t stream)
{
    const int*   adj_rows = (const int*)  d_in[0];
    const int*   adj_cols = (const int*)  d_in[1];
    const float* adj_vals = (const float*)d_in[2];
    const float* Gu0      = (const float*)d_in[3];
    const float* Gi0      = (const float*)d_in[4];
    const float* W_gc     = (const float*)d_in[5];
    const float* b_gc     = (const float*)d_in[6];
    const float* W_bi     = (const float*)d_in[7];
    const float* b_bi     = (const float*)d_in[8];
    const int*   user     = (const int*)  d_in[9];
    const int*   item     = (const int*)  d_in[10];

    float* out = (float*)d_out;

    // workspace (~38.7 MB):
    float*    ego    = (float*)d_ws;                              // 12.8 MB
    float*    side   = ego + (size_t)N_NODES * K;                 // 12.8 MB
    ushort_t* egb    = (ushort_t*)(side + (size_t)N_NODES * K);   // 6.4 MB
    u64_t*    csr64  = (u64_t*)(egb + (size_t)N_NODES * K);       // 6.4 MB
    int*      offs   = (int*)(csr64 + N_EDGES);                   // N_NODES+1
    int*      gbase  = offs + N_NODES + 1;                        // NBUCKET+1
    int*      cursor = gbase + NBUCKET + 1;                       // NBUCKET
    int*      bcnt   = cursor + NBUCKET;                          // NBUCKET
    float*    WT     = (float*)(bcnt + NBUCKET);                  // 96 KB

    // ---- two-level counting sort -> csr64 (col,val) + offs ----
    hipMemsetAsync(bcnt, 0, NBUCKET * sizeof(int), stream);
    bhist_kernel<<<(N_EDGES + A1_CHUNK - 1) / A1_CHUNK, 256, 0, stream>>>(adj_rows, bcnt);
    bscan_kernel<<<1, 256, 0, stream>>>(bcnt, gbase, cursor);
    bscatter_kernel<<<(N_EDGES + A2_CHUNK - 1) / A2_CHUNK, 256, 0, stream>>>(
        adj_rows, adj_cols, adj_vals, cursor, csr64);
    bsort_kernel<<<NBUCKET, 256, 0, stream>>>(gbase, csr64, offs);

    // ---- weight transpose + init ego ----
    wtrans_kernel<<<(3 * 2 * 4096 + 255) / 256, 256, 0, stream>>>(W_gc, W_bi, WT);
    init_ego_kernel<<<(N_NODES * K + 255) / 256, 256, 0, stream>>>(Gu0, Gi0, ego, egb, out);

    // ---- 3 layers ----
    for (int k = 0; k < 3; ++k) {
        gather_kernel<<<N_NODES / 8, 512, 0, stream>>>(
            offs, (const long long*)csr64, egb, side);
        transform_kernel<<<(N_NODES + 63) / 64, 256, 0, stream>>>(
            side, ego, egb,
            WT + (size_t)k * 8192, WT + (size_t)k * 8192 + 4096,
            b_gc + (size_t)k * K, b_bi + (size_t)k * K,
            out, k);
    }

    xui_kernel<<<N_QUERY / 4, 256, 0, stream>>>(user, item, out);
}

// Round 12
// 252.294 us; speedup vs baseline: 1.4046x; 1.0602x over previous
//
#include <hip/hip_runtime.h>

#define NUM_USERS 25000
#define NUM_ITEMS 25000
#define N_NODES   50000
#define N_EDGES   800000
#define K         64
#define N_QUERY   4096
#define LRELU     0.2f

#define NBUCKET   196      // row >> 8 ; 196*256 = 50176 >= 50000
#define A1_CHUNK  8192
#define A2_CHUNK  4096
#define BMAX      4608     // bucket capacity: mean 4096, +8 sigma

typedef unsigned short ushort_t;
typedef unsigned long long u64_t;

// out layout: [ xui (4096) | gu (25000 x 256) | gi (25000 x 256) ]
__device__ __forceinline__ size_t node_out_offset(int n) {
    return (size_t)N_QUERY + (size_t)n * 256;
}

// f32 -> bf16 round-to-nearest-even
__device__ __forceinline__ ushort_t f2bf(float x) {
    unsigned u = __float_as_uint(x);
    return (ushort_t)((u + 0x7FFFu + ((u >> 16) & 1u)) >> 16);
}
__device__ __forceinline__ float bf2f(ushort_t v) {
    return __uint_as_float(((unsigned)v) << 16);
}

// ---------------------------------------------------------------------------
// init (fused): egb = bf16(concat(Gu0,Gi0)); layer-0 block of out (f32);
// weight transpose WT[k][m][o][j] = W_m[k][j][o]
// ---------------------------------------------------------------------------
__global__ __launch_bounds__(256) void init_kernel(
    const float* __restrict__ Gu0, const float* __restrict__ Gi0,
    const float* __restrict__ W_gc, const float* __restrict__ W_bi,
    ushort_t* __restrict__ egb, float* __restrict__ WT, float* __restrict__ out)
{
    int tid = blockIdx.x * 256 + threadIdx.x;
    if (tid < N_NODES * K) {
        int n = tid >> 6;
        int d = tid & 63;
        float v = (n < NUM_USERS) ? Gu0[tid] : Gi0[tid - NUM_USERS * K];
        egb[tid] = f2bf(v);
        out[node_out_offset(n) + d] = v;
    } else {
        int tw = tid - N_NODES * K;
        if (tw < 3 * 2 * 64 * 64) {
            int k   = tw >> 13;
            int m   = (tw >> 12) & 1;
            int idx = tw & 4095;
            int o   = idx >> 6;
            int j   = idx & 63;
            const float* src = m ? W_bi : W_gc;
            WT[tw] = src[k * 4096 + j * 64 + o];
        }
    }
}

// ---------------------------------------------------------------------------
// SORT pass A1: coarse bucket histogram (bucket = row >> 8)
// ---------------------------------------------------------------------------
__global__ __launch_bounds__(256) void bhist_kernel(
    const int* __restrict__ rows, int* __restrict__ bucket_count)
{
    __shared__ int h[NBUCKET];
    int t = threadIdx.x;
    if (t < NBUCKET) h[t] = 0;
    __syncthreads();
    int base = blockIdx.x * A1_CHUNK;
    for (int i = t; i < A1_CHUNK; i += 256) {
        int e = base + i;
        if (e < N_EDGES) atomicAdd(&h[rows[e] >> 8], 1);
    }
    __syncthreads();
    if (t < NBUCKET) atomicAdd(&bucket_count[t], h[t]);
}

// ---------------------------------------------------------------------------
// SORT pass scan: exclusive scan of 196 bucket counts -> gbase(197), cursor
// ---------------------------------------------------------------------------
__global__ __launch_bounds__(256) void bscan_kernel(
    const int* __restrict__ bucket_count,
    int* __restrict__ gbase, int* __restrict__ cursor)
{
    __shared__ int sh[256];
    int t = threadIdx.x;
    sh[t] = (t < NBUCKET) ? bucket_count[t] : 0;
    __syncthreads();
    for (int off = 1; off < 256; off <<= 1) {
        int v = (t >= off) ? sh[t - off] : 0;
        __syncthreads();
        sh[t] += v;
        __syncthreads();
    }
    int excl = (t == 0) ? 0 : sh[t - 1];
    if (t < NBUCKET) { gbase[t] = excl; cursor[t] = excl; }
    if (t == NBUCKET) gbase[NBUCKET] = N_EDGES;
}

// ---------------------------------------------------------------------------
// SORT pass A2: bucket scatter with LDS aggregation (block-exclusive runs)
// ---------------------------------------------------------------------------
__global__ __launch_bounds__(256) void bscatter_kernel(
    const int* __restrict__ rows, const int* __restrict__ cols,
    const float* __restrict__ vals, int* __restrict__ cursor,
    u64_t* __restrict__ csr64)
{
    __shared__ u64_t recs[A2_CHUNK];
    __shared__ int hist[NBUCKET], lbase[NBUCKET], lcur[NBUCKET];
    int t = threadIdx.x;
    if (t < NBUCKET) { hist[t] = 0; lcur[t] = 0; }
    __syncthreads();
    int base = blockIdx.x * A2_CHUNK;
    for (int i = t; i < A2_CHUNK; i += 256) {
        int e = base + i;
        if (e < N_EDGES) {
            int r = rows[e];
            u64_t rec = ((u64_t)(unsigned)__float_as_uint(vals[e]) << 32)
                      | ((u64_t)(unsigned)cols[e] << 16)
                      | (unsigned)r;
            recs[i] = rec;
            atomicAdd(&hist[r >> 8], 1);
        }
    }
    __syncthreads();
    if (t < NBUCKET) lbase[t] = atomicAdd(&cursor[t], hist[t]);
    __syncthreads();
    for (int i = t; i < A2_CHUNK; i += 256) {
        int e = base + i;
        if (e < N_EDGES) {
            u64_t rec = recs[i];
            int b = (int)((rec >> 8) & 0xFF);          // row>>8
            int dst = lbase[b] + atomicAdd(&lcur[b], 1);
            csr64[dst] = rec;
        }
    }
}

// ---------------------------------------------------------------------------
// SORT pass B: per-bucket counting sort (256 bins on row&255) in LDS;
// writes final (col low32, val high32) in place + offs[].
// ---------------------------------------------------------------------------
__global__ __launch_bounds__(256) void bsort_kernel(
    const int* __restrict__ gbase, u64_t* __restrict__ csr64,
    int* __restrict__ offs)
{
    __shared__ u64_t recs[BMAX];
    __shared__ int hist[256], lscan[256], lcur[256];
    int b = blockIdx.x, t = threadIdx.x;
    int g0 = gbase[b];
    int nb = gbase[b + 1] - g0;
    if (nb > BMAX) nb = BMAX;                          // unreachable safety
    hist[t] = 0; lcur[t] = 0;
    __syncthreads();
    for (int i = t; i < nb; i += 256) {
        u64_t rec = csr64[g0 + i];
        recs[i] = rec;
        atomicAdd(&hist[(int)(rec & 0xFF)], 1);        // row & 255
    }
    __syncthreads();
    int v0 = hist[t];
    lscan[t] = v0;
    __syncthreads();
    for (int off = 1; off < 256; off <<= 1) {
        int v = (t >= off) ? lscan[t - off] : 0;
        __syncthreads();
        lscan[t] += v;
        __syncthreads();
    }
    int excl = lscan[t] - v0;                          // exclusive scan
    int row = (b << 8) + t;
    if (row < N_NODES) offs[row] = g0 + excl;
    if (b == 0 && t == 0) offs[N_NODES] = N_EDGES;
    __syncthreads();
    lscan[t] = excl;
    __syncthreads();
    for (int i = t; i < nb; i += 256) {
        u64_t rec = recs[i];
        int rl = (int)(rec & 0xFF);
        int pos = lscan[rl] + atomicAdd(&lcur[rl], 1);
        u64_t outrec = (rec >> 32 << 32) | ((rec >> 16) & 0xFFFFu);
        csr64[g0 + pos] = outrec;
    }
}

// ---------------------------------------------------------------------------
// gather (paired): wave = 1 node; half-waves process 2 edges concurrently.
// Lane loads u32 (2 bf16 dims): 32 lanes cover one edge's whole 128B row.
// 8 loads/iter keep 16 edge-rows (2KB) in flight. f32 accumulate.
// ---------------------------------------------------------------------------
__global__ __launch_bounds__(512, 8) void gather_kernel(
    const int* __restrict__ offs, const long long* __restrict__ csr_cv,
    const unsigned* __restrict__ egb2, float* __restrict__ side)
{
    int t = threadIdx.x;
    int wave = t >> 6;
    int lane = t & 63;
    int par  = lane >> 5;            // which edge of the pair
    int d2   = lane & 31;            // dim-pair index (dims 2*d2, 2*d2+1)
    int node = blockIdx.x * 8 + wave;

    int beg = offs[node];
    int end = offs[node + 1];
    float a0 = 0.f, a1 = 0.f;
    int j = beg;

    for (; j + 16 <= end; j += 16) {               // 8 pairs
        long long cv[8];
        #pragma unroll
        for (int u = 0; u < 8; ++u)
            cv[u] = __builtin_nontemporal_load(csr_cv + j + 2 * u + par);
        unsigned g[8];
        #pragma unroll
        for (int u = 0; u < 8; ++u)
            g[u] = egb2[((size_t)(unsigned)(cv[u] & 0xffffffffLL) << 5) + d2];
        #pragma unroll
        for (int u = 0; u < 8; ++u) {
            float v = __uint_as_float((unsigned)((u64_t)cv[u] >> 32));
            a0 = fmaf(v, bf2f((ushort_t)(g[u] & 0xFFFFu)), a0);
            a1 = fmaf(v, bf2f((ushort_t)(g[u] >> 16)), a1);
        }
    }
    for (; j + 8 <= end; j += 8) {                 // 4 pairs
        long long cv[4];
        #pragma unroll
        for (int u = 0; u < 4; ++u)
            cv[u] = __builtin_nontemporal_load(csr_cv + j + 2 * u + par);
        unsigned g[4];
        #pragma unroll
        for (int u = 0; u < 4; ++u)
            g[u] = egb2[((size_t)(unsigned)(cv[u] & 0xffffffffLL) << 5) + d2];
        #pragma unroll
        for (int u = 0; u < 4; ++u) {
            float v = __uint_as_float((unsigned)((u64_t)cv[u] >> 32));
            a0 = fmaf(v, bf2f((ushort_t)(g[u] & 0xFFFFu)), a0);
            a1 = fmaf(v, bf2f((ushort_t)(g[u] >> 16)), a1);
        }
    }
    for (; j + 2 <= end; j += 2) {                 // 1 pair
        long long cv = __builtin_nontemporal_load(csr_cv + j + par);
        unsigned g = egb2[((size_t)(unsigned)(cv & 0xffffffffLL) << 5) + d2];
        float v = __uint_as_float((unsigned)((u64_t)cv >> 32));
        a0 = fmaf(v, bf2f((ushort_t)(g & 0xFFFFu)), a0);
        a1 = fmaf(v, bf2f((ushort_t)(g >> 16)), a1);
    }
    if (j < end && par == 0) {                     // odd tail edge
        long long cv = __builtin_nontemporal_load(csr_cv + j);
        unsigned g = egb2[((size_t)(unsigned)(cv & 0xffffffffLL) << 5) + d2];
        float v = __uint_as_float((unsigned)((u64_t)cv >> 32));
        a0 = fmaf(v, bf2f((ushort_t)(g & 0xFFFFu)), a0);
        a1 = fmaf(v, bf2f((ushort_t)(g >> 16)), a1);
    }

    a0 += __shfl_xor(a0, 32);                      // combine the two parities
    a1 += __shfl_xor(a1, 32);
    if (par == 0)
        *(float2*)(side + ((size_t)node << 6) + 2 * d2) = make_float2(a0, a1);
}

// ---------------------------------------------------------------------------
// transform: register-tiled f32 GEMM (64 nodes x 64 outs, K=64), 4x4
// micro-tile, XOR-swizzled LDS. ego kept ONLY as bf16 (egb) between kernels.
// Epilogue: bias+lrelu+add, 16-lane norm; writes egb (except last layer) + out.
// ---------------------------------------------------------------------------
__global__ __launch_bounds__(256, 2) void transform_kernel(
    const float* __restrict__ side, ushort_t* __restrict__ egb,
    const float* __restrict__ WgT, const float* __restrict__ WbT,
    const float* __restrict__ bgc, const float* __restrict__ bbi,
    float* __restrict__ out, int layer_k)
{
    __shared__ float s_s [64 * 64];
    __shared__ float s_es[64 * 64];
    __shared__ float s_wg[64 * 64];
    __shared__ float s_wb[64 * 64];

    int t = threadIdx.x;
    int base = blockIdx.x * 64;

    for (int idx = t; idx < 64 * 16; idx += 256) {
        int r = idx >> 4;
        int q = idx & 15;
        int qs = q ^ ((r >> 2) & 7);
        float4 sv = make_float4(0.f, 0.f, 0.f, 0.f);
        float4 ev = make_float4(0.f, 0.f, 0.f, 0.f);
        int node = base + r;
        if (node < N_NODES) {
            sv = *(const float4*)(side + ((size_t)node << 6) + 4 * q);
            ushort4 uv = *(const ushort4*)(egb + ((size_t)node << 6) + 4 * q);
            ev = make_float4(bf2f(uv.x), bf2f(uv.y), bf2f(uv.z), bf2f(uv.w));
        }
        *(float4*)&s_s [r * 64 + 4 * qs] = sv;
        *(float4*)&s_es[r * 64 + 4 * qs] =
            make_float4(ev.x * sv.x, ev.y * sv.y, ev.z * sv.z, ev.w * sv.w);
        *(float4*)&s_wg[r * 64 + 4 * qs] = *(const float4*)(WgT + (size_t)r * 64 + 4 * q);
        *(float4*)&s_wb[r * 64 + 4 * qs] = *(const float4*)(WbT + (size_t)r * 64 + 4 * q);
    }
    __syncthreads();

    const int o0  = (t & 15) << 2;
    const int ln0 = (t >> 4) << 2;
    const int sa  = (t >> 4) & 7;
    const int sw  = t & 7;

    float accg[4][4] = {};
    float accb[4][4] = {};

    #pragma unroll 4
    for (int kq = 0; kq < 16; ++kq) {
        const int qa = (kq ^ sa) << 2;
        const int qw = (kq ^ sw) << 2;
        float4 a[4], b[4], wg[4], wb[4];
        #pragma unroll
        for (int i = 0; i < 4; ++i) {
            a[i] = *(const float4*)&s_s [(ln0 + i) * 64 + qa];
            b[i] = *(const float4*)&s_es[(ln0 + i) * 64 + qa];
        }
        #pragma unroll
        for (int j = 0; j < 4; ++j) {
            wg[j] = *(const float4*)&s_wg[(o0 + j) * 64 + qw];
            wb[j] = *(const float4*)&s_wb[(o0 + j) * 64 + qw];
        }
        #pragma unroll
        for (int i = 0; i < 4; ++i) {
            #pragma unroll
            for (int j = 0; j < 4; ++j) {
                accg[i][j] = fmaf(a[i].x, wg[j].x, accg[i][j]);
                accg[i][j] = fmaf(a[i].y, wg[j].y, accg[i][j]);
                accg[i][j] = fmaf(a[i].z, wg[j].z, accg[i][j]);
                accg[i][j] = fmaf(a[i].w, wg[j].w, accg[i][j]);
                accb[i][j] = fmaf(b[i].x, wb[j].x, accb[i][j]);
                accb[i][j] = fmaf(b[i].y, wb[j].y, accb[i][j]);
                accb[i][j] = fmaf(b[i].z, wb[j].z, accb[i][j]);
                accb[i][j] = fmaf(b[i].w, wb[j].w, accb[i][j]);
            }
        }
    }

    float4 bg4 = *(const float4*)(bgc + o0);
    float4 bb4 = *(const float4*)(bbi + o0);
    float bgv[4] = {bg4.x, bg4.y, bg4.z, bg4.w};
    float bbv[4] = {bb4.x, bb4.y, bb4.z, bb4.w};

    #pragma unroll
    for (int i = 0; i < 4; ++i) {
        int node = base + ln0 + i;
        float en[4];
        float ss = 0.f;
        #pragma unroll
        for (int j = 0; j < 4; ++j) {
            float g = accg[i][j] + bgv[j];
            float h = accb[i][j] + bbv[j];
            g = (g > 0.f) ? g : LRELU * g;
            h = (h > 0.f) ? h : LRELU * h;
            en[j] = g + h;
            ss = fmaf(en[j], en[j], ss);
        }
        #pragma unroll
        for (int m = 1; m < 16; m <<= 1) ss += __shfl_xor(ss, m);
        float inv = rsqrtf(fmaxf(ss, 1e-12f));
        if (node < N_NODES) {
            if (layer_k != 2)
                *(ushort4*)(egb + ((size_t)node << 6) + o0) =
                    make_ushort4(f2bf(en[0]), f2bf(en[1]), f2bf(en[2]), f2bf(en[3]));
            *(float4*)(out + node_out_offset(node) + (size_t)(layer_k + 1) * K + o0) =
                make_float4(en[0] * inv, en[1] * inv, en[2] * inv, en[3] * inv);
        }
    }
}

// ---------------------------------------------------------------------------
// readout: xui[i] = dot(gu[user[i]], gi[item[i]]) over 256 dims
// ---------------------------------------------------------------------------
__global__ __launch_bounds__(256) void xui_kernel(
    const int* __restrict__ user, const int* __restrict__ item,
    float* __restrict__ out)
{
    int idx = blockIdx.x * 4 + (threadIdx.x >> 6);
    if (idx >= N_QUERY) return;
    int lane = threadIdx.x & 63;
    int u  = user[idx];
    int it = item[idx];
    const float4* gu = (const float4*)(out + (size_t)N_QUERY + (size_t)u * 256);
    const float4* gi = (const float4*)(out + (size_t)N_QUERY + (size_t)NUM_USERS * 256
                                           + (size_t)it * 256);
    float4 a = gu[lane];
    float4 b = gi[lane];
    float d = a.x * b.x + a.y * b.y + a.z * b.z + a.w * b.w;
    #pragma unroll
    for (int off = 32; off; off >>= 1) d += __shfl_xor(d, off);
    if (lane == 0) out[idx] = d;
}

extern "C" void kernel_launch(void* const* d_in, const int* in_sizes, int n_in,
                              void* d_out, int out_size, void* d_ws, size_t ws_size,
                              hipStream_t stream)
{
    const int*   adj_rows = (const int*)  d_in[0];
    const int*   adj_cols = (const int*)  d_in[1];
    const float* adj_vals = (const float*)d_in[2];
    const float* Gu0      = (const float*)d_in[3];
    const float* Gi0      = (const float*)d_in[4];
    const float* W_gc     = (const float*)d_in[5];
    const float* b_gc     = (const float*)d_in[6];
    const float* W_bi     = (const float*)d_in[7];
    const float* b_bi     = (const float*)d_in[8];
    const int*   user     = (const int*)  d_in[9];
    const int*   item     = (const int*)  d_in[10];

    float* out = (float*)d_out;

    // workspace (~25.9 MB):
    float*    side   = (float*)d_ws;                              // 12.8 MB
    ushort_t* egb    = (ushort_t*)(side + (size_t)N_NODES * K);   // 6.4 MB
    u64_t*    csr64  = (u64_t*)(egb + (size_t)N_NODES * K);       // 6.4 MB
    int*      offs   = (int*)(csr64 + N_EDGES);                   // N_NODES+1
    int*      gbase  = offs + N_NODES + 1;                        // NBUCKET+1
    int*      cursor = gbase + NBUCKET + 1;                       // NBUCKET
    int*      bcnt   = cursor + NBUCKET;                          // NBUCKET
    float*    WT     = (float*)(bcnt + NBUCKET);                  // 96 KB

    // ---- two-level counting sort -> csr64 (col,val) + offs ----
    hipMemsetAsync(bcnt, 0, NBUCKET * sizeof(int), stream);
    bhist_kernel<<<(N_EDGES + A1_CHUNK - 1) / A1_CHUNK, 256, 0, stream>>>(adj_rows, bcnt);
    bscan_kernel<<<1, 256, 0, stream>>>(bcnt, gbase, cursor);
    bscatter_kernel<<<(N_EDGES + A2_CHUNK - 1) / A2_CHUNK, 256, 0, stream>>>(
        adj_rows, adj_cols, adj_vals, cursor, csr64);
    bsort_kernel<<<NBUCKET, 256, 0, stream>>>(gbase, csr64, offs);

    // ---- fused init (egb + out layer-0 + weight transpose) ----
    {
        int total = N_NODES * K + 3 * 2 * 64 * 64;
        init_kernel<<<(total + 255) / 256, 256, 0, stream>>>(
            Gu0, Gi0, W_gc, W_bi, egb, WT, out);
    }

    // ---- 3 layers ----
    for (int k = 0; k < 3; ++k) {
        gather_kernel<<<N_NODES / 8, 512, 0, stream>>>(
            offs, (const long long*)csr64, (const unsigned*)egb, side);
        transform_kernel<<<(N_NODES + 63) / 64, 256, 0, stream>>>(
            side, egb,
            WT + (size_t)k * 8192, WT + (size_t)k * 8192 + 4096,
            b_gc + (size_t)k * K, b_bi + (size_t)k * K,
            out, k);
    }

    xui_kernel<<<N_QUERY / 4, 256, 0, stream>>>(user, item, out);
}

// Round 13
// 243.956 us; speedup vs baseline: 1.4526x; 1.0342x over previous
//
#include <hip/hip_runtime.h>

#define NUM_USERS 25000
#define NUM_ITEMS 25000
#define N_NODES   50000
#define N_EDGES   800000
#define K         64
#define N_QUERY   4096
#define LRELU     0.2f

#define NBUCKET   196      // row >> 8 ; 196*256 = 50176 >= 50000
#define A1_CHUNK  8192
#define A2_CHUNK  4096
#define BMAX      4608     // bucket capacity: mean 4096, +8 sigma

typedef unsigned short ushort_t;
typedef unsigned long long u64_t;

// out layout: [ xui (4096) | gu (25000 x 256) | gi (25000 x 256) ]
__device__ __forceinline__ size_t node_out_offset(int n) {
    return (size_t)N_QUERY + (size_t)n * 256;
}

// f32 -> bf16 round-to-nearest-even
__device__ __forceinline__ ushort_t f2bf(float x) {
    unsigned u = __float_as_uint(x);
    return (ushort_t)((u + 0x7FFFu + ((u >> 16) & 1u)) >> 16);
}
__device__ __forceinline__ float bf2f(ushort_t v) {
    return __uint_as_float(((unsigned)v) << 16);
}

// ---------------------------------------------------------------------------
// init (fused): egb = bf16(concat(Gu0,Gi0)); layer-0 block of out (f32);
// weight transpose WT[k][m][o][j] = W_m[k][j][o]
// ---------------------------------------------------------------------------
__global__ __launch_bounds__(256) void init_kernel(
    const float* __restrict__ Gu0, const float* __restrict__ Gi0,
    const float* __restrict__ W_gc, const float* __restrict__ W_bi,
    ushort_t* __restrict__ egb, float* __restrict__ WT, float* __restrict__ out)
{
    int tid = blockIdx.x * 256 + threadIdx.x;
    if (tid < N_NODES * K) {
        int n = tid >> 6;
        int d = tid & 63;
        float v = (n < NUM_USERS) ? Gu0[tid] : Gi0[tid - NUM_USERS * K];
        egb[tid] = f2bf(v);
        out[node_out_offset(n) + d] = v;
    } else {
        int tw = tid - N_NODES * K;
        if (tw < 3 * 2 * 64 * 64) {
            int k   = tw >> 13;
            int m   = (tw >> 12) & 1;
            int idx = tw & 4095;
            int o   = idx >> 6;
            int j   = idx & 63;
            const float* src = m ? W_bi : W_gc;
            WT[tw] = src[k * 4096 + j * 64 + o];
        }
    }
}

// ---------------------------------------------------------------------------
// SORT pass A1: coarse bucket histogram (bucket = row >> 8)
// ---------------------------------------------------------------------------
__global__ __launch_bounds__(256) void bhist_kernel(
    const int* __restrict__ rows, int* __restrict__ bucket_count)
{
    __shared__ int h[NBUCKET];
    int t = threadIdx.x;
    if (t < NBUCKET) h[t] = 0;
    __syncthreads();
    int base = blockIdx.x * A1_CHUNK;
    for (int i = t; i < A1_CHUNK; i += 256) {
        int e = base + i;
        if (e < N_EDGES) atomicAdd(&h[rows[e] >> 8], 1);
    }
    __syncthreads();
    if (t < NBUCKET) atomicAdd(&bucket_count[t], h[t]);
}

// ---------------------------------------------------------------------------
// SORT pass scan: exclusive scan of 196 bucket counts -> gbase(197), cursor
// ---------------------------------------------------------------------------
__global__ __launch_bounds__(256) void bscan_kernel(
    const int* __restrict__ bucket_count,
    int* __restrict__ gbase, int* __restrict__ cursor)
{
    __shared__ int sh[256];
    int t = threadIdx.x;
    sh[t] = (t < NBUCKET) ? bucket_count[t] : 0;
    __syncthreads();
    for (int off = 1; off < 256; off <<= 1) {
        int v = (t >= off) ? sh[t - off] : 0;
        __syncthreads();
        sh[t] += v;
        __syncthreads();
    }
    int excl = (t == 0) ? 0 : sh[t - 1];
    if (t < NBUCKET) { gbase[t] = excl; cursor[t] = excl; }
    if (t == NBUCKET) gbase[NBUCKET] = N_EDGES;
}

// ---------------------------------------------------------------------------
// SORT pass A2: bucket scatter with LDS aggregation (block-exclusive runs)
// ---------------------------------------------------------------------------
__global__ __launch_bounds__(256) void bscatter_kernel(
    const int* __restrict__ rows, const int* __restrict__ cols,
    const float* __restrict__ vals, int* __restrict__ cursor,
    u64_t* __restrict__ csr64)
{
    __shared__ u64_t recs[A2_CHUNK];
    __shared__ int hist[NBUCKET], lbase[NBUCKET], lcur[NBUCKET];
    int t = threadIdx.x;
    if (t < NBUCKET) { hist[t] = 0; lcur[t] = 0; }
    __syncthreads();
    int base = blockIdx.x * A2_CHUNK;
    for (int i = t; i < A2_CHUNK; i += 256) {
        int e = base + i;
        if (e < N_EDGES) {
            int r = rows[e];
            u64_t rec = ((u64_t)(unsigned)__float_as_uint(vals[e]) << 32)
                      | ((u64_t)(unsigned)cols[e] << 16)
                      | (unsigned)r;
            recs[i] = rec;
            atomicAdd(&hist[r >> 8], 1);
        }
    }
    __syncthreads();
    if (t < NBUCKET) lbase[t] = atomicAdd(&cursor[t], hist[t]);
    __syncthreads();
    for (int i = t; i < A2_CHUNK; i += 256) {
        int e = base + i;
        if (e < N_EDGES) {
            u64_t rec = recs[i];
            int b = (int)((rec >> 8) & 0xFF);          // row>>8
            int dst = lbase[b] + atomicAdd(&lcur[b], 1);
            csr64[dst] = rec;
        }
    }
}

// ---------------------------------------------------------------------------
// SORT pass B: per-bucket counting sort (256 bins on row&255) in LDS;
// writes final (col low32, val high32) in place + offs[].
// ---------------------------------------------------------------------------
__global__ __launch_bounds__(256) void bsort_kernel(
    const int* __restrict__ gbase, u64_t* __restrict__ csr64,
    int* __restrict__ offs)
{
    __shared__ u64_t recs[BMAX];
    __shared__ int hist[256], lscan[256], lcur[256];
    int b = blockIdx.x, t = threadIdx.x;
    int g0 = gbase[b];
    int nb = gbase[b + 1] - g0;
    if (nb > BMAX) nb = BMAX;                          // unreachable safety
    hist[t] = 0; lcur[t] = 0;
    __syncthreads();
    for (int i = t; i < nb; i += 256) {
        u64_t rec = csr64[g0 + i];
        recs[i] = rec;
        atomicAdd(&hist[(int)(rec & 0xFF)], 1);        // row & 255
    }
    __syncthreads();
    int v0 = hist[t];
    lscan[t] = v0;
    __syncthreads();
    for (int off = 1; off < 256; off <<= 1) {
        int v = (t >= off) ? lscan[t - off] : 0;
        __syncthreads();
        lscan[t] += v;
        __syncthreads();
    }
    int excl = lscan[t] - v0;                          // exclusive scan
    int row = (b << 8) + t;
    if (row < N_NODES) offs[row] = g0 + excl;
    if (b == 0 && t == 0) offs[N_NODES] = N_EDGES;
    __syncthreads();
    lscan[t] = excl;
    __syncthreads();
    for (int i = t; i < nb; i += 256) {
        u64_t rec = recs[i];
        int rl = (int)(rec & 0xFF);
        int pos = lscan[rl] + atomicAdd(&lcur[rl], 1);
        u64_t outrec = (rec >> 32 << 32) | ((rec >> 16) & 0xFFFFu);
        csr64[g0 + pos] = outrec;
    }
}

// ---------------------------------------------------------------------------
// gather (paired, predicated tail): wave = 1 node; half-waves process 2
// edges concurrently; lane loads u32 (2 bf16 dims). Main loop = 8 pairs in
// flight; remainder (<16 edges) handled in ONE predicated 8-pair batch
// (index clamped to end-1, val zeroed) -> no serial tail latency.
// ---------------------------------------------------------------------------
__global__ __launch_bounds__(512, 8) void gather_kernel(
    const int* __restrict__ offs, const long long* __restrict__ csr_cv,
    const unsigned* __restrict__ egb2, float* __restrict__ side)
{
    int t = threadIdx.x;
    int wave = t >> 6;
    int lane = t & 63;
    int par  = lane >> 5;            // which edge of the pair
    int d2   = lane & 31;            // dim-pair index (dims 2*d2, 2*d2+1)
    int node = blockIdx.x * 8 + wave;

    int beg = offs[node];
    int end = offs[node + 1];
    float a0 = 0.f, a1 = 0.f;
    int j = beg;

    for (; j + 16 <= end; j += 16) {               // 8 pairs, all in flight
        long long cv[8];
        #pragma unroll
        for (int u = 0; u < 8; ++u)
            cv[u] = __builtin_nontemporal_load(csr_cv + j + 2 * u + par);
        unsigned g[8];
        #pragma unroll
        for (int u = 0; u < 8; ++u)
            g[u] = egb2[((size_t)(unsigned)(cv[u] & 0xffffffffLL) << 5) + d2];
        #pragma unroll
        for (int u = 0; u < 8; ++u) {
            float v = __uint_as_float((unsigned)((u64_t)cv[u] >> 32));
            a0 = fmaf(v, bf2f((ushort_t)(g[u] & 0xFFFFu)), a0);
            a1 = fmaf(v, bf2f((ushort_t)(g[u] >> 16)), a1);
        }
    }

    if (j < end) {                                 // predicated remainder batch
        long long cv[8];
        bool ok[8];
        #pragma unroll
        for (int u = 0; u < 8; ++u) {
            int idx = j + 2 * u + par;
            ok[u] = idx < end;
            int idxc = ok[u] ? idx : (end - 1);    // clamped: always valid
            cv[u] = __builtin_nontemporal_load(csr_cv + idxc);
        }
        unsigned g[8];
        #pragma unroll
        for (int u = 0; u < 8; ++u)
            g[u] = egb2[((size_t)(unsigned)(cv[u] & 0xffffffffLL) << 5) + d2];
        #pragma unroll
        for (int u = 0; u < 8; ++u) {
            float v = ok[u] ? __uint_as_float((unsigned)((u64_t)cv[u] >> 32)) : 0.f;
            a0 = fmaf(v, bf2f((ushort_t)(g[u] & 0xFFFFu)), a0);
            a1 = fmaf(v, bf2f((ushort_t)(g[u] >> 16)), a1);
        }
    }

    a0 += __shfl_xor(a0, 32);                      // combine the two parities
    a1 += __shfl_xor(a1, 32);
    if (par == 0)
        *(float2*)(side + ((size_t)node << 6) + 2 * d2) = make_float2(a0, a1);
}

// ---------------------------------------------------------------------------
// transform: register-tiled f32 GEMM (64 nodes x 64 outs, K=64), 4x4
// micro-tile, XOR-swizzled LDS. ego kept ONLY as bf16 (egb) between kernels.
// Epilogue: bias+lrelu+add, 16-lane norm; writes egb (except last layer) + out.
// ---------------------------------------------------------------------------
__global__ __launch_bounds__(256, 2) void transform_kernel(
    const float* __restrict__ side, ushort_t* __restrict__ egb,
    const float* __restrict__ WgT, const float* __restrict__ WbT,
    const float* __restrict__ bgc, const float* __restrict__ bbi,
    float* __restrict__ out, int layer_k)
{
    __shared__ float s_s [64 * 64];
    __shared__ float s_es[64 * 64];
    __shared__ float s_wg[64 * 64];
    __shared__ float s_wb[64 * 64];

    int t = threadIdx.x;
    int base = blockIdx.x * 64;

    for (int idx = t; idx < 64 * 16; idx += 256) {
        int r = idx >> 4;
        int q = idx & 15;
        int qs = q ^ ((r >> 2) & 7);
        float4 sv = make_float4(0.f, 0.f, 0.f, 0.f);
        float4 ev = make_float4(0.f, 0.f, 0.f, 0.f);
        int node = base + r;
        if (node < N_NODES) {
            sv = *(const float4*)(side + ((size_t)node << 6) + 4 * q);
            ushort4 uv = *(const ushort4*)(egb + ((size_t)node << 6) + 4 * q);
            ev = make_float4(bf2f(uv.x), bf2f(uv.y), bf2f(uv.z), bf2f(uv.w));
        }
        *(float4*)&s_s [r * 64 + 4 * qs] = sv;
        *(float4*)&s_es[r * 64 + 4 * qs] =
            make_float4(ev.x * sv.x, ev.y * sv.y, ev.z * sv.z, ev.w * sv.w);
        *(float4*)&s_wg[r * 64 + 4 * qs] = *(const float4*)(WgT + (size_t)r * 64 + 4 * q);
        *(float4*)&s_wb[r * 64 + 4 * qs] = *(const float4*)(WbT + (size_t)r * 64 + 4 * q);
    }
    __syncthreads();

    const int o0  = (t & 15) << 2;
    const int ln0 = (t >> 4) << 2;
    const int sa  = (t >> 4) & 7;
    const int sw  = t & 7;

    float accg[4][4] = {};
    float accb[4][4] = {};

    #pragma unroll 4
    for (int kq = 0; kq < 16; ++kq) {
        const int qa = (kq ^ sa) << 2;
        const int qw = (kq ^ sw) << 2;
        float4 a[4], b[4], wg[4], wb[4];
        #pragma unroll
        for (int i = 0; i < 4; ++i) {
            a[i] = *(const float4*)&s_s [(ln0 + i) * 64 + qa];
            b[i] = *(const float4*)&s_es[(ln0 + i) * 64 + qa];
        }
        #pragma unroll
        for (int j = 0; j < 4; ++j) {
            wg[j] = *(const float4*)&s_wg[(o0 + j) * 64 + qw];
            wb[j] = *(const float4*)&s_wb[(o0 + j) * 64 + qw];
        }
        #pragma unroll
        for (int i = 0; i < 4; ++i) {
            #pragma unroll
            for (int j = 0; j < 4; ++j) {
                accg[i][j] = fmaf(a[i].x, wg[j].x, accg[i][j]);
                accg[i][j] = fmaf(a[i].y, wg[j].y, accg[i][j]);
                accg[i][j] = fmaf(a[i].z, wg[j].z, accg[i][j]);
                accg[i][j] = fmaf(a[i].w, wg[j].w, accg[i][j]);
                accb[i][j] = fmaf(b[i].x, wb[j].x, accb[i][j]);
                accb[i][j] = fmaf(b[i].y, wb[j].y, accb[i][j]);
                accb[i][j] = fmaf(b[i].z, wb[j].z, accb[i][j]);
                accb[i][j] = fmaf(b[i].w, wb[j].w, accb[i][j]);
            }
        }
    }

    float4 bg4 = *(const float4*)(bgc + o0);
    float4 bb4 = *(const float4*)(bbi + o0);
    float bgv[4] = {bg4.x, bg4.y, bg4.z, bg4.w};
    float bbv[4] = {bb4.x, bb4.y, bb4.z, bb4.w};

    #pragma unroll
    for (int i = 0; i < 4; ++i) {
        int node = base + ln0 + i;
        float en[4];
        float ss = 0.f;
        #pragma unroll
        for (int j = 0; j < 4; ++j) {
            float g = accg[i][j] + bgv[j];
            float h = accb[i][j] + bbv[j];
            g = (g > 0.f) ? g : LRELU * g;
            h = (h > 0.f) ? h : LRELU * h;
            en[j] = g + h;
            ss = fmaf(en[j], en[j], ss);
        }
        #pragma unroll
        for (int m = 1; m < 16; m <<= 1) ss += __shfl_xor(ss, m);
        float inv = rsqrtf(fmaxf(ss, 1e-12f));
        if (node < N_NODES) {
            if (layer_k != 2)
                *(ushort4*)(egb + ((size_t)node << 6) + o0) =
                    make_ushort4(f2bf(en[0]), f2bf(en[1]), f2bf(en[2]), f2bf(en[3]));
            *(float4*)(out + node_out_offset(node) + (size_t)(layer_k + 1) * K + o0) =
                make_float4(en[0] * inv, en[1] * inv, en[2] * inv, en[3] * inv);
        }
    }
}

// ---------------------------------------------------------------------------
// readout: xui[i] = dot(gu[user[i]], gi[item[i]]) over 256 dims
// ---------------------------------------------------------------------------
__global__ __launch_bounds__(256) void xui_kernel(
    const int* __restrict__ user, const int* __restrict__ item,
    float* __restrict__ out)
{
    int idx = blockIdx.x * 4 + (threadIdx.x >> 6);
    if (idx >= N_QUERY) return;
    int lane = threadIdx.x & 63;
    int u  = user[idx];
    int it = item[idx];
    const float4* gu = (const float4*)(out + (size_t)N_QUERY + (size_t)u * 256);
    const float4* gi = (const float4*)(out + (size_t)N_QUERY + (size_t)NUM_USERS * 256
                                           + (size_t)it * 256);
    float4 a = gu[lane];
    float4 b = gi[lane];
    float d = a.x * b.x + a.y * b.y + a.z * b.z + a.w * b.w;
    #pragma unroll
    for (int off = 32; off; off >>= 1) d += __shfl_xor(d, off);
    if (lane == 0) out[idx] = d;
}

extern "C" void kernel_launch(void* const* d_in, const int* in_sizes, int n_in,
                              void* d_out, int out_size, void* d_ws, size_t ws_size,
                              hipStream_t stream)
{
    const int*   adj_rows = (const int*)  d_in[0];
    const int*   adj_cols = (const int*)  d_in[1];
    const float* adj_vals = (const float*)d_in[2];
    const float* Gu0      = (const float*)d_in[3];
    const float* Gi0      = (const float*)d_in[4];
    const float* W_gc     = (const float*)d_in[5];
    const float* b_gc     = (const float*)d_in[6];
    const float* W_bi     = (const float*)d_in[7];
    const float* b_bi     = (const float*)d_in[8];
    const int*   user     = (const int*)  d_in[9];
    const int*   item     = (const int*)  d_in[10];

    float* out = (float*)d_out;

    // workspace (~25.9 MB):
    float*    side   = (float*)d_ws;                              // 12.8 MB
    ushort_t* egb    = (ushort_t*)(side + (size_t)N_NODES * K);   // 6.4 MB
    u64_t*    csr64  = (u64_t*)(egb + (size_t)N_NODES * K);       // 6.4 MB
    int*      offs   = (int*)(csr64 + N_EDGES);                   // N_NODES+1
    int*      gbase  = offs + N_NODES + 1;                        // NBUCKET+1
    int*      cursor = gbase + NBUCKET + 1;                       // NBUCKET
    int*      bcnt   = cursor + NBUCKET;                          // NBUCKET
    float*    WT     = (float*)(bcnt + NBUCKET);                  // 96 KB

    // ---- two-level counting sort -> csr64 (col,val) + offs ----
    hipMemsetAsync(bcnt, 0, NBUCKET * sizeof(int), stream);
    bhist_kernel<<<(N_EDGES + A1_CHUNK - 1) / A1_CHUNK, 256, 0, stream>>>(adj_rows, bcnt);
    bscan_kernel<<<1, 256, 0, stream>>>(bcnt, gbase, cursor);
    bscatter_kernel<<<(N_EDGES + A2_CHUNK - 1) / A2_CHUNK, 256, 0, stream>>>(
        adj_rows, adj_cols, adj_vals, cursor, csr64);
    bsort_kernel<<<NBUCKET, 256, 0, stream>>>(gbase, csr64, offs);

    // ---- fused init (egb + out layer-0 + weight transpose) ----
    {
        int total = N_NODES * K + 3 * 2 * 64 * 64;
        init_kernel<<<(total + 255) / 256, 256, 0, stream>>>(
            Gu0, Gi0, W_gc, W_bi, egb, WT, out);
    }

    // ---- 3 layers ----
    for (int k = 0; k < 3; ++k) {
        gather_kernel<<<N_NODES / 8, 512, 0, stream>>>(
            offs, (const long long*)csr64, (const unsigned*)egb, side);
        transform_kernel<<<(N_NODES + 63) / 64, 256, 0, stream>>>(
            side, egb,
            WT + (size_t)k * 8192, WT + (size_t)k * 8192 + 4096,
            b_gc + (size_t)k * K, b_bi + (size_t)k * K,
            out, k);
    }

    xui_kernel<<<N_QUERY / 4, 256, 0, stream>>>(user, item, out);
}